// Round 1
// baseline (406.848 us; speedup 1.0000x reference)
//
#include <hip/hip_runtime.h>
#include <math.h>

#define Bn 2048
#define Sn 277
#define Rn 80
#define Ln 12
#define Zn 56
#define NROWS (Bn * Sn)        // 567296
#define NBLK1 (NROWS / 256)    // 2216 exactly

// ws layout (bytes):
//   [0, 17728)          double bce_partial[2216]   (fully written, no zeroing needed)
//   [17728, 17952)      float  ws_avg[56]          (atomic accum -> memset to 0)
//   [17952, 30496)      float  ws_var[3136]        (atomic accum -> memset to 0)

// select bit j from the 80-bit mask held in b0,b1,b2 (j is compile-time after unroll)
#define BITAT(jj) ((((jj) < 32 ? (b0 >> (jj)) : ((jj) < 64 ? (b1 >> ((jj) - 32)) : (b2 >> ((jj) - 64)))) & 1u) != 0u)

__global__ __launch_bounds__(256) void bce_kernel(
    const float* __restrict__ x, const float* __restrict__ recon,
    const float* __restrict__ masks, const int* __restrict__ lhs_ind,
    double* __restrict__ bce_partial)
{
    __shared__ unsigned int sbits[Ln][4];
    __shared__ int slhs[Rn];
    __shared__ float swsum[4];

    const int tid = threadIdx.x;

    // Build 80-bit masks (3 x u32 per lhs) from the float mask matrix.
    if (tid < Ln * 3) {
        int l = tid / 3, w = tid % 3;
        unsigned int bits = 0u;
        for (int b = 0; b < 32; ++b) {
            int j = w * 32 + b;
            if (j < Rn && masks[l * Rn + j] > 0.5f) bits |= (1u << b);
        }
        sbits[l][w] = bits;
    }
    if (tid < Rn) slhs[tid] = lhs_ind[tid];
    __syncthreads();

    const int row = blockIdx.x * 256 + tid;   // grid is exact: row < NROWS always

    // Pass 1: argmax of one-hot x row (value is exactly 1.0 at the true rule).
    const float4* xp = (const float4*)(x + (size_t)row * Rn);
    int amax = 0;
    #pragma unroll
    for (int k = 0; k < 20; ++k) {
        float4 v = xp[k];
        if (v.x > 0.5f) amax = 4 * k + 0;
        if (v.y > 0.5f) amax = 4 * k + 1;
        if (v.z > 0.5f) amax = 4 * k + 2;
        if (v.w > 0.5f) amax = 4 * k + 3;
    }
    const int l = slhs[amax];
    const unsigned int b0 = sbits[l][0], b1 = sbits[l][1], b2 = sbits[l][2];

    // Pass 2: masked recon row into registers + denominator.
    float vals[Rn];
    float denom = 0.0f;
    const float4* rp = (const float4*)(recon + (size_t)row * Rn);
    #pragma unroll
    for (int k = 0; k < 20; ++k) {
        float4 v = rp[k];
        const int j = 4 * k;
        float e0 = BITAT(j + 0) ? v.x : 0.0f;
        float e1 = BITAT(j + 1) ? v.y : 0.0f;
        float e2 = BITAT(j + 2) ? v.z : 0.0f;
        float e3 = BITAT(j + 3) ? v.w : 0.0f;
        vals[j + 0] = e0; vals[j + 1] = e1; vals[j + 2] = e2; vals[j + 3] = e3;
        denom += (e0 + e1) + (e2 + e3);
    }

    // Pass 3: sum of clamped log(1 - t) over all r, plus correction for r == amax.
    const float invd = 1.0f / denom;
    float ta = 1.0f;
    float ssum = 0.0f;
    #pragma unroll
    for (int j = 0; j < Rn; ++j) {
        float t = vals[j] * invd;
        t = fminf(t, 1.0f);                         // guard log(negative) -> NaN
        ssum += fmaxf(__logf(1.0f - t), -100.0f);   // __logf(0) = -inf -> clamp -100
        ta = (j == amax) ? t : ta;                  // predicated capture, no dyn-index
    }
    const float la  = fmaxf(__logf(ta), -100.0f);
    const float lpa = fmaxf(__logf(1.0f - ta), -100.0f);
    float contrib = (ssum - lpa) + la;

    // Block reduction -> one double partial per block (deterministic, no atomics).
    #pragma unroll
    for (int o = 32; o > 0; o >>= 1) contrib += __shfl_down(contrib, o, 64);
    if ((tid & 63) == 0) swsum[tid >> 6] = contrib;
    __syncthreads();
    if (tid == 0)
        bce_partial[blockIdx.x] = (double)((swsum[0] + swsum[1]) + (swsum[2] + swsum[3]));
}

__global__ __launch_bounds__(256) void moments_kernel(
    const float* __restrict__ mu, float* __restrict__ ws_var, float* __restrict__ ws_avg)
{
    __shared__ float sm[64 * Zn];   // 14336 B
    const int tid = threadIdx.x;
    const int r0 = blockIdx.x * 64;

    for (int i = tid; i < 64 * Zn; i += 256) sm[i] = mu[(size_t)r0 * Zn + i];
    __syncthreads();

    // var partial: mu^T mu over this 64-row chunk
    for (int p = tid; p < Zn * Zn; p += 256) {
        int i = p / Zn, j = p % Zn;
        float acc = 0.0f;
        for (int r = 0; r < 64; ++r) acc = fmaf(sm[r * Zn + i], sm[r * Zn + j], acc);
        atomicAdd(&ws_var[p], acc);
    }
    // column-sum partial for avg_mu
    if (tid < Zn) {
        float acc = 0.0f;
        for (int r = 0; r < 64; ++r) acc += sm[r * Zn + tid];
        atomicAdd(&ws_avg[tid], acc);
    }
}

__global__ __launch_bounds__(256) void finalize_kernel(
    const double* __restrict__ bce_partial, const float* __restrict__ ws_var,
    const float* __restrict__ ws_avg, float* __restrict__ out)
{
    __shared__ double sb[4];
    __shared__ float sv[4], sa[4];
    const int tid = threadIdx.x;

    double bsum = 0.0;
    for (int i = tid; i < NBLK1; i += 256) bsum += bce_partial[i];

    float vsum = 0.0f;
    for (int p = tid; p < Zn * Zn; p += 256) {
        int i = p / Zn, j = p % Zn;
        float v = ws_var[p] * (1.0f / (float)Bn) - ((i == j) ? 1.0f : 0.0f);
        vsum += fabsf(v);
    }
    float asum = 0.0f;
    for (int z = tid; z < Zn; z += 256) { float a = ws_avg[z]; asum += a * a; }

    #pragma unroll
    for (int o = 32; o > 0; o >>= 1) {
        bsum += __shfl_down(bsum, o, 64);
        vsum += __shfl_down(vsum, o, 64);
        asum += __shfl_down(asum, o, 64);
    }
    if ((tid & 63) == 0) { int w = tid >> 6; sb[w] = bsum; sv[w] = vsum; sa[w] = asum; }
    __syncthreads();
    if (tid == 0) {
        double tb = (sb[0] + sb[1]) + (sb[2] + sb[3]);
        double tv = (double)((sv[0] + sv[1]) + (sv[2] + sv[3]));
        double ta = (double)((sa[0] + sa[1]) + (sa[2] + sa[3]));
        double bce = -tb / ((double)Sn * (double)Bn);
        double mom = ta / ((double)Bn * (double)Bn * (double)Zn)
                   + tv / ((double)Zn * (double)Zn);
        out[0] = (float)(bce + mom);
    }
}

extern "C" void kernel_launch(void* const* d_in, const int* in_sizes, int n_in,
                              void* d_out, int out_size, void* d_ws, size_t ws_size,
                              hipStream_t stream)
{
    const float* x     = (const float*)d_in[0];
    const float* recon = (const float*)d_in[1];
    const float* mu    = (const float*)d_in[2];
    // d_in[3] = log_var: unused by the reference
    const float* masks = (const float*)d_in[4];
    const int*   lhs   = (const int*)d_in[5];
    float* out = (float*)d_out;

    char* ws = (char*)d_ws;
    double* bce_partial = (double*)ws;
    float* ws_avg = (float*)(ws + 17728);
    float* ws_var = (float*)(ws + 17952);

    // zero only the atomic-accumulator region (ws is poisoned 0xAA each call)
    hipMemsetAsync(ws + 17728, 0, 224 + 12544, stream);

    bce_kernel<<<NBLK1, 256, 0, stream>>>(x, recon, masks, lhs, bce_partial);
    moments_kernel<<<Bn / 64, 256, 0, stream>>>(mu, ws_var, ws_avg);
    finalize_kernel<<<1, 256, 0, stream>>>(bce_partial, ws_var, ws_avg, out);
}